// Round 6
// baseline (215.532 us; speedup 1.0000x reference)
//
#include <hip/hip_runtime.h>

#define Bn 128
#define Vn 128000
#define SLICES 8
#define SLICE_LEN 16000      // Vn/SLICES
#define TPB 256
#define GRIDN (Bn*SLICES)    // 1024 blocks
#define NB1 512              // L1 bins: K>>21 (e<=1 -> bin<=508)
#define NB1P 516             // padded copy stride (bank spread)
#define NB2 512              // sub-bins: K bits [20:12]
#define CAP 512              // cut-sub gather cap
#define CAPM 16384           // merged bin-level candidate cap per row
#define CAPB 4096            // q4 bin-level candidate cap per row
#define LCAP 3072            // per-block LDS staging cap (24KB)
#define FMINV -3.4028234663852886e38f
#define FOUT  -3.3895313892515355e38f
#define FIXS 268435456.0     // 2^28
#define FIXI (1.0/268435456.0)
#define SUMMASK ((1ULL<<45)-1)

// ---- ws arena (bytes) ----
#define OFF_ROWS   0u
#define OFF_SLICEM 65536u
#define OFF_L1P    81920u                 // u64 packed [Bn][NB1] = 512KB
#define OFF_LCNT   606208u                // u32 [Bn][8]
#define OFF_LISTS  610304u                // u64 [Bn][CAPM] = 16MB (merged)
#define OFF_Q4BIG  17387520u              // u64 [Bn][CAPB] = 4MB
#define ZERO_U64   66048u                 // (OFF_LISTS-OFF_L1P)/8

// Unnormalized e = exp2((v-M)*c1), c1 = log2e/T, computed EVERYWHERE via
// __fsub_rn/__fmul_rn/exp2f (no contraction) -> bit-identical K across phases,
// so no Kc cache is needed. L1 histogram u64 fixed point:
// [count:19 | round(sum*2^28):45] -> order-exact integer atomics.
struct RowWS {
  double Zd;
  float S2f, t4;
  unsigned thrBits;
  int q4mode, token;
  unsigned v0; int i0; unsigned v2; int i2;
  unsigned cutBin[5];
  unsigned CbefB[4]; double SbefB[4];
  double Sbef4;
};

// ---- phase-overlaid LDS ----
struct SmMax    { float sF[4]; };
struct SmHist   { unsigned long long hP[4*NB1P]; float sM; };
struct SmCollect{ unsigned long long Lbuf[LCAP]; double wT[4]; unsigned wTc[4];
                  int mx0,mx1,mx2,mnz; unsigned sCut[4]; unsigned lCnt,gBase; float sM; };
struct SmResolve{ double hS[NB2]; unsigned hC[NB2]; unsigned long long Ls[CAP];
                  double wT[4]; unsigned wTc[4]; int mx,mnz,gcnt;
                  double sSexc; unsigned sCexc;
                  unsigned shVS[4]; int shIS[4]; double shSK[4]; double sT4d; };
struct SmPick   { double hS[NB2]; unsigned hC[NB2]; unsigned long long Ls[CAP];
                  double wT[4]; unsigned wTc[4]; int mx,mnz,mcnt; double sSbS; };
struct SmOut    { float sM; };
#define SMEMSZ 24704

__device__ inline void dec(unsigned long long p, double& s, unsigned& c){
  c = (unsigned)(p >> 45);
  s = (double)(p & SUMMASK) * FIXI;
}

__device__ inline unsigned kbits(float v, float M, float c1){
  float d = __fsub_rn(v, M);
  float x = __fmul_rn(d, c1);
  return __float_as_uint(exp2f(x));
}

// wave-aggregated global append
__device__ inline void wappend(bool pred, unsigned long long e,
                               unsigned* cnt, unsigned long long* dst, unsigned cap){
  unsigned long long mask = __ballot(pred);
  if (!mask) return;
  int lane = threadIdx.x & 63;
  int leader = __builtin_ctzll(mask);
  unsigned base = 0;
  if (lane == leader) base = atomicAdd(cnt, (unsigned)__popcll(mask));
  base = __shfl(base, leader);
  if (pred){
    unsigned pos = base + (unsigned)__popcll(mask & ((1ULL << lane) - 1ULL));
    if (pos < cap) dst[pos] = e;
  }
}

// 256-thread suffix-inclusive scan over 512 (s,c); thread t owns 2t,2t+1.
__device__ inline void sufscan512(int tid, double s0, unsigned c0, double s1, unsigned c1,
    double& S0i, unsigned& C0i, double& S1i, unsigned& C1i, double& St,
    double* wT, unsigned* wTc){
  __syncthreads();
  int lane = tid & 63, wv = tid >> 6;
  double vS = s0 + s1; unsigned vC = c0 + c1;
  #pragma unroll
  for (int off = 1; off < 64; off <<= 1){
    double tS = __shfl_down(vS, off); unsigned tC = __shfl_down(vC, off);
    if (lane + off < 64){ vS += tS; vC += tC; }
  }
  if (lane == 0){ wT[wv] = vS; wTc[wv] = vC; }
  __syncthreads();
  double add = 0.0; unsigned addc = 0u;
  for (int w = wv + 1; w < 4; ++w){ add += wT[w]; addc += wTc[w]; }
  S0i = vS + add; C0i = vC + addc;
  S1i = S0i - s0; C1i = C0i - c0;
  St = wT[0] + wT[1] + wT[2] + wT[3];
}

// ================= phases =================

__device__ void phMaxZero(const float* __restrict__ logits, float* sliceM,
                          unsigned long long* wsz, char* smc){
  {
    size_t i = (size_t)blockIdx.x*TPB + threadIdx.x;
    size_t st = (size_t)gridDim.x*TPB;
    for (; i < ZERO_U64; i += st) wsz[i] = 0ull;
  }
  SmMax* sm = (SmMax*)smc;
  int blk = blockIdx.x, b = blk >> 3, sl = blk & 7, tid = threadIdx.x;
  const float4* l4 = (const float4*)(logits + (size_t)b*Vn + sl*SLICE_LEN);
  float m = -3.4e38f;
  for (int j = tid; j < SLICE_LEN/4; j += TPB){
    float4 v = l4[j];
    m = fmaxf(m, fmaxf(fmaxf(v.x, v.y), fmaxf(v.z, v.w)));
  }
  #pragma unroll
  for (int o = 32; o; o >>= 1) m = fmaxf(m, __shfl_down(m, o));
  if ((tid & 63) == 0) sm->sF[tid >> 6] = m;
  __syncthreads();
  if (tid == 0){
    float mm = sm->sF[0];
    for (int w = 1; w < 4; ++w) mm = fmaxf(mm, sm->sF[w]);
    sliceM[b*SLICES + sl] = mm;
  }
}

__device__ void phHist(const float* __restrict__ logits, const float* __restrict__ temps,
                       const float* __restrict__ sliceM, unsigned long long* L1P, char* smc){
  SmHist* sm = (SmHist*)smc;
  int blk = blockIdx.x, b = blk >> 3, sl = blk & 7, tid = threadIdx.x;
  int cp = tid & 3;                       // per-lane copy spread
  for (int i = tid; i < 4*NB1P; i += TPB) sm->hP[i] = 0ull;
  float T = temps[b];
  float c1 = 1.4426950408889634f / T;
  if (tid == 0){
    float M = sliceM[b*SLICES];
    for (int s = 1; s < SLICES; ++s) M = fmaxf(M, sliceM[b*SLICES + s]);
    sm->sM = M;
  }
  __syncthreads();
  float M = sm->sM;
  const float4* l4 = (const float4*)(logits + (size_t)b*Vn + sl*SLICE_LEN);
  for (int j = tid; j < SLICE_LEN/4; j += TPB){
    float4 v = l4[j];
    unsigned k0 = kbits(v.x, M, c1), k1 = kbits(v.y, M, c1);
    unsigned k2 = kbits(v.z, M, c1), k3 = kbits(v.w, M, c1);
    unsigned b0 = min(k0 >> 21, NB1-1u), b1 = min(k1 >> 21, NB1-1u);
    unsigned b2 = min(k2 >> 21, NB1-1u), b3 = min(k3 >> 21, NB1-1u);
    unsigned long long f0 = (unsigned long long)((double)__uint_as_float(k0) * FIXS + 0.5) + (1ULL<<45);
    unsigned long long f1 = (unsigned long long)((double)__uint_as_float(k1) * FIXS + 0.5) + (1ULL<<45);
    unsigned long long f2 = (unsigned long long)((double)__uint_as_float(k2) * FIXS + 0.5) + (1ULL<<45);
    unsigned long long f3 = (unsigned long long)((double)__uint_as_float(k3) * FIXS + 0.5) + (1ULL<<45);
    atomicAdd(&sm->hP[cp*NB1P + b0], f0);
    atomicAdd(&sm->hP[cp*NB1P + b1], f1);
    atomicAdd(&sm->hP[cp*NB1P + b2], f2);
    atomicAdd(&sm->hP[cp*NB1P + b3], f3);
  }
  __syncthreads();
  for (int bin = tid; bin < NB1; bin += TPB){
    unsigned long long c = sm->hP[bin] + sm->hP[NB1P+bin] + sm->hP[2*NB1P+bin] + sm->hP[3*NB1P+bin];
    if (c) atomicAdd(&L1P[(size_t)b*NB1 + bin], c);
  }
}

__device__ void phCollect(const float* __restrict__ logits, const float* __restrict__ temps,
    const float* __restrict__ sliceM, const unsigned long long* __restrict__ L1P, RowWS* rows,
    const int* __restrict__ top_ks, const float* __restrict__ top_ps,
    const float* __restrict__ top_ps2, const float* __restrict__ min_ps,
    unsigned long long* lists, unsigned* lcnt, char* smc){
  SmCollect* sm = (SmCollect*)smc;
  int blk = blockIdx.x, b = blk >> 3, sl = blk & 7, tid = threadIdx.x;
  RowWS& R = rows[b];
  float T = temps[b];
  float c1 = 1.4426950408889634f / T;
  if (tid == 0){
    sm->mx0 = -1; sm->mx1 = -1; sm->mx2 = -1; sm->mnz = NB1; sm->lCnt = 0u;
    float M = sliceM[b*SLICES];
    for (int s = 1; s < SLICES; ++s) M = fmaxf(M, sliceM[b*SLICES + s]);
    sm->sM = M;
  }
  int B0 = 2*tid, B1 = 2*tid+1;
  double s0, s1; unsigned c0, c1u;
  dec(L1P[(size_t)b*NB1 + B0], s0, c0);
  dec(L1P[(size_t)b*NB1 + B1], s1, c1u);
  double S0i, S1i, St; unsigned C0i, C1i;
  sufscan512(tid, s0, c0, s1, c1u, S0i, C0i, S1i, C1i, St, sm->wT, sm->wTc);
  float M = sm->sM;
  float minp = min_ps[b];
  unsigned thrBits = __float_as_uint(minp);
  int thrBin = (int)(thrBits >> 21); if (thrBin > NB1-1) thrBin = NB1-1;
  unsigned k = (unsigned)top_ks[b];
  double tZ1 = (double)top_ps[b] * St, tZ2 = (double)top_ps2[b] * St;
  if (c0){ if (C0i >= k) atomicMax(&sm->mx0,B0); if (S0i > tZ1) atomicMax(&sm->mx1,B0); if (S0i > tZ2) atomicMax(&sm->mx2,B0); atomicMin(&sm->mnz,B0); }
  if (c1u){ if (C1i >= k) atomicMax(&sm->mx0,B1); if (S1i > tZ1) atomicMax(&sm->mx1,B1); if (S1i > tZ2) atomicMax(&sm->mx2,B1); atomicMin(&sm->mnz,B1); }
  __syncthreads();
  int w0 = sm->mx0;
  int w1 = (sm->mx1 >= 0) ? sm->mx1 : sm->mnz;
  int w2 = (sm->mx2 >= 0) ? sm->mx2 : sm->mnz;
  if (tid == 0){
    sm->sCut[0]=(unsigned)w0; sm->sCut[1]=(unsigned)w1; sm->sCut[2]=(unsigned)w2; sm->sCut[3]=(unsigned)thrBin;
    if (sl == 0){
      R.thrBits = thrBits; R.Zd = St;
      R.cutBin[0]=(unsigned)w0; R.cutBin[1]=(unsigned)w1; R.cutBin[2]=(unsigned)w2; R.cutBin[3]=(unsigned)thrBin;
    }
  }
  if (sl == 0){
    #define PUB(qi, wq) { if (B0==(wq)){ R.CbefB[qi]=C0i-c0; R.SbefB[qi]=S0i-s0; } else if (B1==(wq)){ R.CbefB[qi]=C1i-c1u; R.SbefB[qi]=S1i-s1; } }
    PUB(0, w0) PUB(1, w1) PUB(2, w2) PUB(3, thrBin)
    #undef PUB
  }
  __syncthreads();
  unsigned tb0 = sm->sCut[0], tb1 = sm->sCut[1], tb2 = sm->sCut[2], tb3 = sm->sCut[3];
  int base = sl*SLICE_LEN;
  const float4* l4 = (const float4*)(logits + (size_t)b*Vn + base);
  unsigned long long* dst = lists + (size_t)b*CAPM;
  unsigned* gc = &lcnt[b*8+0];
  for (int j = tid; j < SLICE_LEN/4; j += TPB){
    float4 v = l4[j];
    unsigned kk[4];
    kk[0] = kbits(v.x, M, c1); kk[1] = kbits(v.y, M, c1);
    kk[2] = kbits(v.z, M, c1); kk[3] = kbits(v.w, M, c1);
    #pragma unroll
    for (int c = 0; c < 4; ++c){
      unsigned K = kk[c];
      unsigned bin = K >> 21;
      bool pr = (bin == tb0) | (bin == tb1) | (bin == tb2) | (bin == tb3);
      if (pr){
        unsigned long long e = (((unsigned long long)(~K)) << 32) | (unsigned)(base + j*4 + c);
        unsigned pos = atomicAdd(&sm->lCnt, 1u);
        if (pos < LCAP) sm->Lbuf[pos] = e;
        else { unsigned gp = atomicAdd(gc, 1u); if (gp < CAPM) dst[gp] = e; }
      }
    }
  }
  __syncthreads();
  unsigned cnt = sm->lCnt; if (cnt > LCAP) cnt = LCAP;
  if (tid == 0) sm->gBase = atomicAdd(gc, cnt);
  __syncthreads();
  unsigned gb = sm->gBase;
  for (unsigned i = tid; i < cnt; i += TPB){
    unsigned p = gb + i;
    if (p < CAPM) dst[p] = sm->Lbuf[i];
  }
}

__device__ void phResolve(RowWS* rows,
    const unsigned long long* __restrict__ lists, const unsigned* __restrict__ lcnt,
    const unsigned long long* __restrict__ L1P,
    const int* __restrict__ top_ks, const float* __restrict__ top_ps,
    const float* __restrict__ top_ps2, const float* __restrict__ uarr, char* smc){
  int b = blockIdx.x;
  if (b >= Bn) return;
  SmResolve* sm = (SmResolve*)smc;
  int t = threadIdx.x;
  RowWS& R = rows[b];
  unsigned thrBits = R.thrBits; double Zd = R.Zd;
  int k = top_ks[b];
  double tauP = (double)top_ps[b] * Zd, tauP2 = (double)top_ps2[b] * Zd;
  int n = (int)lcnt[b*8+0]; if (n > CAPM) n = CAPM;
  const unsigned long long* L = lists + (size_t)b*CAPM;
  int B0 = 2*t, B1 = 2*t+1;
  for (int q = 0; q < 4; ++q){
    if (q == 2 && tauP2 == tauP && R.cutBin[2] == R.cutBin[1]){
      if (t == 0){ sm->shVS[2] = sm->shVS[1]; sm->shIS[2] = sm->shIS[1]; sm->shSK[2] = sm->shSK[1]; }
      __syncthreads();
      continue;
    }
    sm->hS[B0] = 0.0; sm->hS[B1] = 0.0; sm->hC[B0] = 0u; sm->hC[B1] = 0u;
    if (t == 0){ sm->mx = -1; sm->mnz = NB2; sm->gcnt = 0; }
    __syncthreads();
    unsigned tb = R.cutBin[q];
    for (int j = t; j < n; j += TPB){
      unsigned K = ~(unsigned)(L[j] >> 32);
      if ((K >> 21) == tb){
        unsigned sub = (K >> 12) & (NB2-1);
        unsafeAtomicAdd(&sm->hS[sub], (double)__uint_as_float(K));
        atomicAdd(&sm->hC[sub], 1u);
      }
    }
    __syncthreads();
    double s0 = sm->hS[B0], s1 = sm->hS[B1];
    unsigned c0 = sm->hC[B0], c1u = sm->hC[B1];
    double S0i, S1i, St; unsigned C0i, C1i;
    sufscan512(t, s0, c0, s1, c1u, S0i, C0i, S1i, C1i, St, sm->wT, sm->wTc);
    unsigned baseC = R.CbefB[q]; double baseS = R.SbefB[q];
    int w;
    if (q == 3){
      w = (int)((thrBits >> 12) & (NB2-1));
    } else {
      if (c0){
        if (q == 0){ if (baseC + C0i >= (unsigned)k) atomicMax(&sm->mx, B0); }
        else { double tau = (q == 1) ? tauP : tauP2; if (baseS + S0i > tau) atomicMax(&sm->mx, B0); }
        atomicMin(&sm->mnz, B0);
      }
      if (c1u){
        if (q == 0){ if (baseC + C1i >= (unsigned)k) atomicMax(&sm->mx, B1); }
        else { double tau = (q == 1) ? tauP : tauP2; if (baseS + S1i > tau) atomicMax(&sm->mx, B1); }
        atomicMin(&sm->mnz, B1);
      }
      __syncthreads();
      w = (sm->mx >= 0) ? sm->mx : sm->mnz;
    }
    if (B0 == w){ sm->sSexc = baseS + (S0i - s0); sm->sCexc = baseC + (C0i - c0); }
    else if (B1 == w){ sm->sSexc = baseS + (S1i - s1); sm->sCexc = baseC + (C1i - c1u); }
    unsigned pre = (tb << 9) | (unsigned)w;
    for (int j = t; j < n; j += TPB){
      unsigned long long e = L[j];
      unsigned K = ~(unsigned)(e >> 32);
      if ((K >> 12) == pre){
        int p = atomicAdd(&sm->gcnt, 1);
        if (p < CAP) sm->Ls[p] = e;
      }
    }
    __syncthreads();
    if (t == 0){
      int m = sm->gcnt; if (m > CAP) m = CAP;
      for (int i2 = 1; i2 < m; ++i2){
        unsigned long long key = sm->Ls[i2]; int j = i2-1;
        while (j >= 0 && sm->Ls[j] > key){ sm->Ls[j+1] = sm->Ls[j]; --j; }
        sm->Ls[j+1] = key;
      }
      double S = sm->sSexc;
      if (q == 0){
        if (m > 0){
          int mm = k - (int)sm->sCexc; if (mm < 1) mm = 1; if (mm > m) mm = m;
          for (int j = 0; j < mm; ++j){ unsigned K = ~(unsigned)(sm->Ls[j] >> 32); S += (double)__uint_as_float(K); }
          unsigned long long e = sm->Ls[mm-1];
          sm->shVS[0] = ~(unsigned)(e >> 32); sm->shIS[0] = (int)(unsigned)(e & 0xFFFFFFFFu); sm->shSK[0] = S;
        } else { sm->shVS[0] = 0u; sm->shIS[0] = 0x7FFFFFFF; sm->shSK[0] = S; }
      } else if (q < 3){
        double tau = (q == 1) ? tauP : tauP2;
        int last = -1;
        for (int j = 0; j < m; ++j){
          if (S > tau) break;
          unsigned K = ~(unsigned)(sm->Ls[j] >> 32);
          S += (double)__uint_as_float(K); last = j;
        }
        if (m > 0){
          int pick = (last < 0) ? 0 : last;
          unsigned long long e = sm->Ls[pick];
          sm->shVS[q] = ~(unsigned)(e >> 32); sm->shIS[q] = (int)(unsigned)(e & 0xFFFFFFFFu); sm->shSK[q] = S;
        } else { sm->shVS[q] = 0u; sm->shIS[q] = 0x7FFFFFFF; sm->shSK[q] = S; }
      } else {
        for (int j = 0; j < m; ++j){
          unsigned K = ~(unsigned)(sm->Ls[j] >> 32);
          if (K < thrBits) break;
          S += (double)__uint_as_float(K);
        }
        sm->shVS[3] = thrBits; sm->shIS[3] = 0x7FFFFFFF; sm->shSK[3] = S;
      }
    }
    __syncthreads();
  }
  // combine + q4 L1 walk
  if (t == 0){
    unsigned v0 = sm->shVS[0]; int i0 = sm->shIS[0]; double tot = sm->shSK[0];
    if (sm->shVS[1] > v0 || (sm->shVS[1] == v0 && sm->shIS[1] < i0)){ v0 = sm->shVS[1]; i0 = sm->shIS[1]; tot = sm->shSK[1]; }
    if (sm->shVS[3] > v0 || (sm->shVS[3] == v0 && sm->shIS[3] < i0)){ v0 = sm->shVS[3]; i0 = sm->shIS[3]; tot = sm->shSK[3]; }
    R.v0 = v0; R.i0 = i0;
    R.v2 = sm->shVS[2]; R.i2 = sm->shIS[2]; R.S2f = (float)sm->shSK[2];
    float t4 = uarr[b] * (float)tot;
    R.t4 = t4;
    sm->sT4d = (double)t4;
    sm->mx = -1;
  }
  double s0, s1; unsigned c0, c1u;
  dec(L1P[(size_t)b*NB1 + B0], s0, c0);
  dec(L1P[(size_t)b*NB1 + B1], s1, c1u);
  double S0i, S1i, St; unsigned C0i, C1i;
  sufscan512(t, s0, c0, s1, c1u, S0i, C0i, S1i, C1i, St, sm->wT, sm->wTc);
  double t4d = sm->sT4d;
  if (c0 && S0i >= t4d) atomicMax(&sm->mx, B0);
  if (c1u && S1i >= t4d) atomicMax(&sm->mx, B1);
  __syncthreads();
  int w = sm->mx;
  if (w < 0){
    if (t == 0){ R.q4mode = 2; R.token = R.i0; }
  } else {
    if (t == 0) R.q4mode = 0;
    if (B0 == w){ R.cutBin[4] = (unsigned)w; R.Sbef4 = S0i - s0; }
    else if (B1 == w){ R.cutBin[4] = (unsigned)w; R.Sbef4 = S1i - s1; }
  }
}

__device__ void phOut(const float* __restrict__ logits, const float* __restrict__ temps,
    const float* __restrict__ sliceM, const RowWS* __restrict__ rows,
    unsigned long long* q4big, unsigned* lcnt, float* __restrict__ outLp, char* smc){
  SmOut* sm = (SmOut*)smc;
  int blk = blockIdx.x, b = blk >> 3, sl = blk & 7, tid = threadIdx.x;
  unsigned v2 = rows[b].v2; int i2v = rows[b].i2; float S2f = rows[b].S2f;
  float lgS2 = logf(S2f);
  bool doColl = (rows[b].q4mode == 0);
  unsigned tb4 = rows[b].cutBin[4];
  float T = temps[b];
  float c1 = 1.4426950408889634f / T;
  if (tid == 0){
    float M = sliceM[b*SLICES];
    for (int s = 1; s < SLICES; ++s) M = fmaxf(M, sliceM[b*SLICES + s]);
    sm->sM = M;
  }
  __syncthreads();
  float M = sm->sM;
  int base = sl*SLICE_LEN;
  const float4* l4 = (const float4*)(logits + (size_t)b*Vn + base);
  float4* O4 = (float4*)(outLp + (size_t)b*Vn + base);
  unsigned long long* dst = q4big + (size_t)b*CAPB;
  unsigned* lc = &lcnt[b*8+4];
  for (int j = tid; j < SLICE_LEN/4; j += TPB){
    float4 v = l4[j];
    unsigned kk[4];
    kk[0] = kbits(v.x, M, c1); kk[1] = kbits(v.y, M, c1);
    kk[2] = kbits(v.z, M, c1); kk[3] = kbits(v.w, M, c1);
    float4 o;
    #pragma unroll
    for (int c = 0; c < 4; ++c){
      unsigned K = kk[c];
      int i = base + j*4 + c;
      bool pr = doColl && ((K >> 21) == tb4);
      wappend(pr, (((unsigned long long)(~K)) << 32) | (unsigned)i, lc, dst, CAPB);
      float p = __uint_as_float(K);
      float val = (K > v2 || (K == v2 && i <= i2v)) ? fmaxf(logf(p) - lgS2, FMINV) : FOUT;
      if (c==0) o.x = val; else if (c==1) o.y = val; else if (c==2) o.z = val; else o.w = val;
    }
    O4[j] = o;
  }
}

__device__ void phPick(RowWS* rows, const unsigned long long* __restrict__ q4big,
    const unsigned* __restrict__ lcnt, float* __restrict__ outTok,
    float* __restrict__ outNtlp, char* smc){
  int b = blockIdx.x;
  if (b >= Bn) return;
  SmPick* sm = (SmPick*)smc;
  int t = threadIdx.x;
  RowWS& R = rows[b];
  int token = -1; unsigned pB = 0u; int have = 0;
  if (R.q4mode == 2){
    if (t == 0){ token = R.token; pB = R.v0; have = 1; }
  } else {
    int n = (int)lcnt[b*8+4]; if (n > CAPB) n = CAPB;
    int B0 = 2*t, B1 = 2*t+1;
    sm->hS[B0] = 0.0; sm->hS[B1] = 0.0; sm->hC[B0] = 0u; sm->hC[B1] = 0u;
    if (t == 0){ sm->mx = -1; sm->mnz = NB2; sm->mcnt = 0; }
    __syncthreads();
    for (int j = t; j < n; j += TPB){
      unsigned K = ~(unsigned)(q4big[(size_t)b*CAPB + j] >> 32);
      unsigned sub = (K >> 12) & (NB2-1);
      unsafeAtomicAdd(&sm->hS[sub], (double)__uint_as_float(K));
      atomicAdd(&sm->hC[sub], 1u);
    }
    __syncthreads();
    double s0 = sm->hS[B0], s1 = sm->hS[B1];
    unsigned c0 = sm->hC[B0], c1u = sm->hC[B1];
    double S0i, S1i, St; unsigned C0i, C1i;
    sufscan512(t, s0, c0, s1, c1u, S0i, C0i, S1i, C1i, St, sm->wT, sm->wTc);
    double baseS = R.Sbef4, t4d = (double)R.t4;
    if (c0){ if (baseS + S0i >= t4d) atomicMax(&sm->mx, B0); atomicMin(&sm->mnz, B0); }
    if (c1u){ if (baseS + S1i >= t4d) atomicMax(&sm->mx, B1); atomicMin(&sm->mnz, B1); }
    __syncthreads();
    int w = (sm->mx >= 0) ? sm->mx : ((sm->mnz < NB2) ? sm->mnz : -1);
    if (w < 0){
      if (t == 0){ token = R.i0; pB = R.v0; have = 1; }
    } else {
      if (B0 == w) sm->sSbS = baseS + (S0i - s0);
      else if (B1 == w) sm->sSbS = baseS + (S1i - s1);
      for (int j = t; j < n; j += TPB){
        unsigned long long e = q4big[(size_t)b*CAPB + j];
        unsigned K = ~(unsigned)(e >> 32);
        if (((K >> 12) & (NB2-1)) == (unsigned)w){
          int p = atomicAdd(&sm->mcnt, 1);
          if (p < CAP) sm->Ls[p] = e;
        }
      }
      __syncthreads();
      if (t == 0){
        int m = sm->mcnt; if (m > CAP) m = CAP;
        for (int i2 = 1; i2 < m; ++i2){
          unsigned long long key = sm->Ls[i2]; int j = i2-1;
          while (j >= 0 && sm->Ls[j] > key){ sm->Ls[j+1] = sm->Ls[j]; --j; }
          sm->Ls[j+1] = key;
        }
        double S = sm->sSbS, t4dd = (double)R.t4;
        unsigned v0 = R.v0; int i0 = R.i0;
        token = -1; pB = R.v0;
        for (int j = 0; j < m; ++j){
          unsigned K = ~(unsigned)(sm->Ls[j] >> 32);
          int idx = (int)(unsigned)(sm->Ls[j] & 0xFFFFFFFFu);
          bool kept = (K > v0) || (K == v0 && idx <= i0);
          if (!kept){ token = i0; pB = v0; break; }
          S += (double)__uint_as_float(K);
          if (S >= t4dd){ token = idx; pB = K; break; }
        }
        if (token < 0){ token = i0; pB = v0; }
        have = 1;
      }
    }
  }
  if (have){
    unsigned v2 = R.v2; int i2v = R.i2;
    bool kept2 = (pB > v2) || (pB == v2 && token <= i2v);
    float pt = __uint_as_float(pB);
    float lp = kept2 ? fmaxf(logf(pt) - logf(R.S2f), FMINV) : FOUT;
    outTok[b] = (float)token;
    outNtlp[b] = lp;
  }
}

// ================= kernels (plain 6-dispatch chain) =================
__global__ __launch_bounds__(TPB) void k_f0(const float* __restrict__ logits, float* sliceM,
    unsigned long long* L1P){
  __shared__ __align__(16) char sm[SMEMSZ];
  phMaxZero(logits, sliceM, L1P, sm);
}
__global__ __launch_bounds__(TPB) void k_f1(const float* __restrict__ logits,
    const float* __restrict__ temps, const float* __restrict__ sliceM, unsigned long long* L1P){
  __shared__ __align__(16) char sm[SMEMSZ];
  phHist(logits, temps, sliceM, L1P, sm);
}
__global__ __launch_bounds__(TPB) void k_f2(const float* __restrict__ logits,
    const float* __restrict__ temps, const float* __restrict__ sliceM,
    const unsigned long long* __restrict__ L1P, RowWS* rows,
    const int* __restrict__ top_ks, const float* __restrict__ top_ps,
    const float* __restrict__ top_ps2, const float* __restrict__ min_ps,
    unsigned long long* lists, unsigned* lcnt){
  __shared__ __align__(16) char sm[SMEMSZ];
  phCollect(logits, temps, sliceM, L1P, rows, top_ks, top_ps, top_ps2, min_ps, lists, lcnt, sm);
}
__global__ __launch_bounds__(TPB) void k_f3(RowWS* rows,
    const unsigned long long* __restrict__ lists, const unsigned* __restrict__ lcnt,
    const unsigned long long* __restrict__ L1P,
    const int* __restrict__ top_ks, const float* __restrict__ top_ps,
    const float* __restrict__ top_ps2, const float* __restrict__ uarr){
  __shared__ __align__(16) char sm[SMEMSZ];
  phResolve(rows, lists, lcnt, L1P, top_ks, top_ps, top_ps2, uarr, sm);
}
__global__ __launch_bounds__(TPB) void k_f4(const float* __restrict__ logits,
    const float* __restrict__ temps, const float* __restrict__ sliceM,
    const RowWS* __restrict__ rows, unsigned long long* q4big, unsigned* lcnt,
    float* __restrict__ outLp){
  __shared__ __align__(16) char sm[SMEMSZ];
  phOut(logits, temps, sliceM, rows, q4big, lcnt, outLp, sm);
}
__global__ __launch_bounds__(TPB) void k_f5(RowWS* rows,
    const unsigned long long* __restrict__ q4big, const unsigned* __restrict__ lcnt,
    float* __restrict__ outTok, float* __restrict__ outNtlp){
  __shared__ __align__(16) char sm[SMEMSZ];
  phPick(rows, q4big, lcnt, outTok, outNtlp, sm);
}

extern "C" void kernel_launch(void* const* d_in, const int* in_sizes, int n_in,
                              void* d_out, int out_size, void* d_ws, size_t ws_size,
                              hipStream_t stream)
{
  const float* logits  = (const float*)d_in[0];
  const float* temps   = (const float*)d_in[1];
  const int*   top_ks  = (const int*)d_in[2];
  const float* top_ps  = (const float*)d_in[3];
  const float* top_ps2 = (const float*)d_in[4];
  const float* min_ps  = (const float*)d_in[5];
  const float* uarr    = (const float*)d_in[6];

  char* ws = (char*)d_ws;
  RowWS*    rows   = (RowWS*)(ws + OFF_ROWS);
  float*    sliceM = (float*)(ws + OFF_SLICEM);
  unsigned long long* L1P   = (unsigned long long*)(ws + OFF_L1P);
  unsigned* lcnt   = (unsigned*)(ws + OFF_LCNT);
  unsigned long long* lists = (unsigned long long*)(ws + OFF_LISTS);
  unsigned long long* q4big = (unsigned long long*)(ws + OFF_Q4BIG);

  float* outTok  = (float*)d_out;
  float* outLp   = outTok + Bn;
  float* outNtlp = outLp + (size_t)Bn * Vn;

  k_f0<<<GRIDN, TPB, 0, stream>>>(logits, sliceM, L1P);
  k_f1<<<GRIDN, TPB, 0, stream>>>(logits, temps, sliceM, L1P);
  k_f2<<<GRIDN, TPB, 0, stream>>>(logits, temps, sliceM, L1P, rows, top_ks, top_ps, top_ps2, min_ps, lists, lcnt);
  k_f3<<<Bn,    TPB, 0, stream>>>(rows, lists, lcnt, L1P, top_ks, top_ps, top_ps2, uarr);
  k_f4<<<GRIDN, TPB, 0, stream>>>(logits, temps, sliceM, rows, q4big, lcnt, outLp);
  k_f5<<<Bn,    TPB, 0, stream>>>(rows, q4big, lcnt, outTok, outNtlp);
}